// Round 1
// baseline (1591.190 us; speedup 1.0000x reference)
//
#include <hip/hip_runtime.h>
#include <math.h>

#define B_ 8
#define N_ 2048
#define DIM 512
#define HEADS 8
#define DHEAD 64
#define TOKENS (B_ * N_)                 // 16384
#define SZ ((size_t)TOKENS * DIM)        // 8388608 floats per [B,*,512]-sized buffer
#define SCALE_ 8.0f
#define EPS_ 1e-12f
#define SQRT_DIM 22.62741699796952f      // sqrt(512)

// ---------------------------------------------------------------------------
// K1: RMSNorm  xn = x / max(||x||,eps) * g * sqrt(512).  One wave per token.
// ---------------------------------------------------------------------------
__global__ __launch_bounds__(256) void rmsnorm_k(const float* __restrict__ x,
                                                 const float* __restrict__ g,
                                                 float* __restrict__ xn) {
    const int wave = threadIdx.x >> 6;
    const int lane = threadIdx.x & 63;
    const size_t t = (size_t)blockIdx.x * 4 + wave;
    const float4* xp = (const float4*)(x + t * DIM + lane * 8);
    float4 v0 = xp[0], v1 = xp[1];
    float ss = v0.x * v0.x + v0.y * v0.y + v0.z * v0.z + v0.w * v0.w +
               v1.x * v1.x + v1.y * v1.y + v1.z * v1.z + v1.w * v1.w;
#pragma unroll
    for (int off = 32; off; off >>= 1) ss += __shfl_xor(ss, off);
    const float s = SQRT_DIM / fmaxf(sqrtf(ss), EPS_);
    const float4* gp = (const float4*)(g + lane * 8);
    float4 g0 = gp[0], g1 = gp[1];
    float4 o0, o1;
    o0.x = v0.x * s * g0.x; o0.y = v0.y * s * g0.y;
    o0.z = v0.z * s * g0.z; o0.w = v0.w * s * g0.w;
    o1.x = v1.x * s * g1.x; o1.y = v1.y * s * g1.y;
    o1.z = v1.z * s * g1.z; o1.w = v1.w * s * g1.w;
    float4* op = (float4*)(xn + t * DIM + lane * 8);
    op[0] = o0; op[1] = o1;
}

// ---------------------------------------------------------------------------
// K2: QKV GEMM  [16384,512] @ [512,1536], epilogue scatters to q/k/v [B,H,N,64].
// 128x128 tile, BK=16, 256 threads, 8x8 micro-tile.
// ---------------------------------------------------------------------------
__global__ __launch_bounds__(256) void qkv_gemm_k(const float* __restrict__ A,
                                                  const float* __restrict__ Bw,
                                                  float* __restrict__ qkv) {
    __shared__ float As[16][132];   // transposed: As[k][m]
    __shared__ float Bs[16][132];   // natural:    Bs[k][n]
    const int row0 = blockIdx.y * 128;
    const int col0 = blockIdx.x * 128;
    const int tid = threadIdx.x;
    const int ty = tid >> 4, tx = tid & 15;
    const int ar = tid >> 1, ak = (tid & 1) * 8;   // A-stage: row, k-offset
    const int br = tid >> 4, bc = (tid & 15) * 8;  // B-stage: k-row, col-offset
    float acc[8][8] = {};
    for (int k0 = 0; k0 < DIM; k0 += 16) {
        const float* ap = A + (size_t)(row0 + ar) * DIM + k0 + ak;
        float4 a0 = ((const float4*)ap)[0];
        float4 a1 = ((const float4*)ap)[1];
        const float* bp = Bw + (size_t)(k0 + br) * 1536 + col0 + bc;
        float4 b0 = ((const float4*)bp)[0];
        float4 b1 = ((const float4*)bp)[1];
        __syncthreads();
        As[ak + 0][ar] = a0.x; As[ak + 1][ar] = a0.y;
        As[ak + 2][ar] = a0.z; As[ak + 3][ar] = a0.w;
        As[ak + 4][ar] = a1.x; As[ak + 5][ar] = a1.y;
        As[ak + 6][ar] = a1.z; As[ak + 7][ar] = a1.w;
        *(float4*)&Bs[br][bc] = b0;
        *(float4*)&Bs[br][bc + 4] = b1;
        __syncthreads();
#pragma unroll 4
        for (int kk = 0; kk < 16; ++kk) {
            float4 aA = *(const float4*)&As[kk][ty * 8];
            float4 aB = *(const float4*)&As[kk][ty * 8 + 4];
            float4 bA = *(const float4*)&Bs[kk][tx * 8];
            float4 bB = *(const float4*)&Bs[kk][tx * 8 + 4];
            float av[8] = {aA.x, aA.y, aA.z, aA.w, aB.x, aB.y, aB.z, aB.w};
            float bv[8] = {bA.x, bA.y, bA.z, bA.w, bB.x, bB.y, bB.z, bB.w};
#pragma unroll
            for (int i = 0; i < 8; ++i)
#pragma unroll
                for (int j = 0; j < 8; ++j)
                    acc[i][j] = fmaf(av[i], bv[j], acc[i][j]);
        }
    }
    // scatter: col c -> which = c/512, h = (c%512)/64, d = c%64
    const int cbase = col0 + tx * 8;
    const int which = cbase / 512;
    const int h = (cbase % 512) / 64;
    const int d0 = cbase % 64;     // multiple of 8, fits within one head
    float* ob = qkv + (size_t)which * SZ;
#pragma unroll
    for (int i = 0; i < 8; ++i) {
        const int m = row0 + ty * 8 + i;
        const int b = m >> 11, n = m & 2047;
        float* p = ob + ((((size_t)b * HEADS + h) * N_ + n) * DHEAD + d0);
        *(float4*)p = make_float4(acc[i][0], acc[i][1], acc[i][2], acc[i][3]);
        *(float4*)(p + 4) = make_float4(acc[i][4], acc[i][5], acc[i][6], acc[i][7]);
    }
}

// ---------------------------------------------------------------------------
// K3: per-(b,h,n) l2norm over 64 dims, * scale.  One wave per row, in place.
// ---------------------------------------------------------------------------
__global__ __launch_bounds__(256) void qknorm_k(float* __restrict__ buf,
                                                const float* __restrict__ scale) {
    const int wave = threadIdx.x >> 6;
    const int lane = threadIdx.x & 63;
    const size_t row = (size_t)blockIdx.x * 4 + wave;
    float v = buf[row * DHEAD + lane];
    float ss = v * v;
#pragma unroll
    for (int off = 32; off; off >>= 1) ss += __shfl_xor(ss, off);
    const float inv = 1.0f / fmaxf(sqrtf(ss), EPS_);
    buf[row * DHEAD + lane] = v * inv * scale[lane];
}

// ---------------------------------------------------------------------------
// K4: attention for one (b,h), 64-query tile, streaming over 32 key tiles.
// Scores bounded: |qhat.khat| <= 1 -> logits in [-8,8]; no max subtraction.
// S-GEMM: queries->tx, keys->ty.  P stored [key][query] (reuses K buffer).
// PV-GEMM: queries->ty, dd->tx; denom accumulated from P fragments directly.
// ---------------------------------------------------------------------------
__global__ __launch_bounds__(256) void attn_k(const float* __restrict__ q,
                                              const float* __restrict__ k,
                                              const float* __restrict__ v,
                                              float* __restrict__ o) {
    __shared__ float Qt[64][64];   // Qt[d][query]
    __shared__ float KP[64][68];   // phase 1: Kt[d][key]; phase 2: Pt[key][query]
    __shared__ float Vs[64][68];   // Vs[key][dd]
    const int bh = blockIdx.y;
    const int q0 = blockIdx.x * 64;
    const int tid = threadIdx.x;
    const int ty = tid >> 4, tx = tid & 15;
    const int sr = tid >> 2, sd = (tid & 3) * 16;    // staging: row, d-offset
    const size_t base = (size_t)bh * (N_ * DHEAD);
    // stage Q transposed (once)
    {
        const float4* qp = (const float4*)(q + base + (size_t)(q0 + sr) * DHEAD + sd);
#pragma unroll
        for (int u = 0; u < 4; ++u) {
            float4 t4 = qp[u];
            Qt[sd + u * 4 + 0][sr] = t4.x;
            Qt[sd + u * 4 + 1][sr] = t4.y;
            Qt[sd + u * 4 + 2][sr] = t4.z;
            Qt[sd + u * 4 + 3][sr] = t4.w;
        }
    }
    float oacc[4][4] = {};
    float dsum[4] = {};
    for (int kt = 0; kt < N_ / 64; ++kt) {
        const float4* kp = (const float4*)(k + base + (size_t)(kt * 64 + sr) * DHEAD + sd);
        const float4* vp = (const float4*)(v + base + (size_t)(kt * 64 + sr) * DHEAD + sd);
        float4 kf[4], vf[4];
#pragma unroll
        for (int u = 0; u < 4; ++u) { kf[u] = kp[u]; vf[u] = vp[u]; }
        __syncthreads();                       // prev iter done reading KP/Vs
#pragma unroll
        for (int u = 0; u < 4; ++u) {
            KP[sd + u * 4 + 0][sr] = kf[u].x;
            KP[sd + u * 4 + 1][sr] = kf[u].y;
            KP[sd + u * 4 + 2][sr] = kf[u].z;
            KP[sd + u * 4 + 3][sr] = kf[u].w;
            *(float4*)&Vs[sr][sd + u * 4] = vf[u];
        }
        __syncthreads();
        // S[key][query]: s[i][j], key = 4ty+i, query = 4tx+j
        float s[4][4] = {};
#pragma unroll 8
        for (int d = 0; d < 64; ++d) {
            float4 kq = *(const float4*)&KP[d][ty * 4];
            float4 qq = *(const float4*)&Qt[d][tx * 4];
            float av[4] = {kq.x, kq.y, kq.z, kq.w};
            float bv[4] = {qq.x, qq.y, qq.z, qq.w};
#pragma unroll
            for (int i = 0; i < 4; ++i)
#pragma unroll
                for (int j = 0; j < 4; ++j)
                    s[i][j] = fmaf(av[i], bv[j], s[i][j]);
        }
        float p[4][4];
#pragma unroll
        for (int i = 0; i < 4; ++i)
#pragma unroll
            for (int j = 0; j < 4; ++j)
                p[i][j] = __expf(SCALE_ * s[i][j]);
        __syncthreads();                       // everyone done reading KP as Kt
#pragma unroll
        for (int i = 0; i < 4; ++i)
            *(float4*)&KP[ty * 4 + i][tx * 4] =
                make_float4(p[i][0], p[i][1], p[i][2], p[i][3]);
        __syncthreads();
        // PV: O[query][dd], query = 4ty+i, dd = 4tx+jj
#pragma unroll 8
        for (int jk = 0; jk < 64; ++jk) {
            float4 pv = *(const float4*)&KP[jk][ty * 4];
            float4 vv = *(const float4*)&Vs[jk][tx * 4];
            float av[4] = {pv.x, pv.y, pv.z, pv.w};
            float bv[4] = {vv.x, vv.y, vv.z, vv.w};
#pragma unroll
            for (int i = 0; i < 4; ++i) {
#pragma unroll
                for (int jj = 0; jj < 4; ++jj)
                    oacc[i][jj] = fmaf(av[i], bv[jj], oacc[i][jj]);
                dsum[i] += av[i];
            }
        }
    }
#pragma unroll
    for (int i = 0; i < 4; ++i) {
        const float inv = 1.0f / dsum[i];
        float* p = o + base + (size_t)(q0 + ty * 4 + i) * DHEAD + tx * 4;
        *(float4*)p = make_float4(oacc[i][0] * inv, oacc[i][1] * inv,
                                  oacc[i][2] * inv, oacc[i][3] * inv);
    }
}

// ---------------------------------------------------------------------------
// K5: out GEMM  [16384,512] @ [512,512] -> d_out, A gathered from [B,H,N,64].
// ---------------------------------------------------------------------------
__global__ __launch_bounds__(256) void out_gemm_k(const float* __restrict__ Ain,
                                                  const float* __restrict__ Bw,
                                                  float* __restrict__ C) {
    __shared__ float As[16][132];
    __shared__ float Bs[16][132];
    const int row0 = blockIdx.y * 128;
    const int col0 = blockIdx.x * 128;
    const int tid = threadIdx.x;
    const int ty = tid >> 4, tx = tid & 15;
    const int ar = tid >> 1, ak = (tid & 1) * 8;
    const int br = tid >> 4, bc = (tid & 15) * 8;
    const int m_ = row0 + ar;
    const int ab = m_ >> 11, an = m_ & 2047;
    float acc[8][8] = {};
    for (int k0 = 0; k0 < DIM; k0 += 16) {
        const int c0 = k0 + ak;                 // hidden index, multiple of 8
        const int h = c0 >> 6, d0 = c0 & 63;
        const float* ap = Ain + ((((size_t)ab * HEADS + h) * N_ + an) * DHEAD + d0);
        float4 a0 = ((const float4*)ap)[0];
        float4 a1 = ((const float4*)ap)[1];
        const float* bp = Bw + (size_t)(k0 + br) * DIM + col0 + bc;
        float4 b0 = ((const float4*)bp)[0];
        float4 b1 = ((const float4*)bp)[1];
        __syncthreads();
        As[ak + 0][ar] = a0.x; As[ak + 1][ar] = a0.y;
        As[ak + 2][ar] = a0.z; As[ak + 3][ar] = a0.w;
        As[ak + 4][ar] = a1.x; As[ak + 5][ar] = a1.y;
        As[ak + 6][ar] = a1.z; As[ak + 7][ar] = a1.w;
        *(float4*)&Bs[br][bc] = b0;
        *(float4*)&Bs[br][bc + 4] = b1;
        __syncthreads();
#pragma unroll 4
        for (int kk = 0; kk < 16; ++kk) {
            float4 aA = *(const float4*)&As[kk][ty * 8];
            float4 aB = *(const float4*)&As[kk][ty * 8 + 4];
            float4 bA = *(const float4*)&Bs[kk][tx * 8];
            float4 bB = *(const float4*)&Bs[kk][tx * 8 + 4];
            float av[8] = {aA.x, aA.y, aA.z, aA.w, aB.x, aB.y, aB.z, aB.w};
            float bv[8] = {bA.x, bA.y, bA.z, bA.w, bB.x, bB.y, bB.z, bB.w};
#pragma unroll
            for (int i = 0; i < 8; ++i)
#pragma unroll
                for (int j = 0; j < 8; ++j)
                    acc[i][j] = fmaf(av[i], bv[j], acc[i][j]);
        }
    }
#pragma unroll
    for (int i = 0; i < 8; ++i) {
        const int m = row0 + ty * 8 + i;
        float* p = C + (size_t)m * DIM + col0 + tx * 8;
        *(float4*)p = make_float4(acc[i][0], acc[i][1], acc[i][2], acc[i][3]);
        *(float4*)(p + 4) = make_float4(acc[i][4], acc[i][5], acc[i][6], acc[i][7]);
    }
}

// ---------------------------------------------------------------------------
extern "C" void kernel_launch(void* const* d_in, const int* in_sizes, int n_in,
                              void* d_out, int out_size, void* d_ws, size_t ws_size,
                              hipStream_t stream) {
    const float* x       = (const float*)d_in[0];
    const float* g       = (const float*)d_in[1];
    const float* w_qkv   = (const float*)d_in[2];
    const float* q_scale = (const float*)d_in[3];
    const float* k_scale = (const float*)d_in[4];
    const float* w_out   = (const float*)d_in[5];
    float* out = (float*)d_out;
    float* ws  = (float*)d_ws;

    if (ws_size < 4 * SZ * sizeof(float)) return;   // need 128 MiB scratch

    float* xn = ws;             // [16384,512]
    float* qb = ws + SZ;        // q [B,H,N,64]
    float* kb = ws + 2 * SZ;    // k
    float* vb = ws + 3 * SZ;    // v
    float* ao = ws;             // attn out, reuses xn slot (xn dead after K2)

    rmsnorm_k<<<TOKENS / 4, 256, 0, stream>>>(x, g, xn);
    qkv_gemm_k<<<dim3(1536 / 128, TOKENS / 128), 256, 0, stream>>>(xn, w_qkv, qb);
    qknorm_k<<<(TOKENS * HEADS) / 4, 256, 0, stream>>>(qb, q_scale);
    qknorm_k<<<(TOKENS * HEADS) / 4, 256, 0, stream>>>(kb, k_scale);
    attn_k<<<dim3(N_ / 64, B_ * HEADS), 256, 0, stream>>>(qb, kb, vb, ao);
    out_gemm_k<<<dim3(DIM / 128, TOKENS / 128), 256, 0, stream>>>(ao, w_out, out);
}

// Round 4
// 922.937 us; speedup vs baseline: 1.7240x; 1.7240x over previous
//
#include <hip/hip_runtime.h>
#include <math.h>

#define B_ 8
#define N_ 2048
#define DIM 512
#define HEADS 8
#define DHEAD 64
#define TOKENS (B_ * N_)                 // 16384
#define SZ ((size_t)TOKENS * DIM)        // 8388608 floats per [B,*,512]-sized buffer
#define SCALE_ 8.0f
#define EPS_ 1e-12f
#define SQRT_DIM 22.62741699796952f      // sqrt(512)

typedef unsigned long long u64;
typedef __attribute__((ext_vector_type(8))) short s8v;     // 8 bf16 (4 VGPR)
typedef __attribute__((ext_vector_type(16))) float f16v;   // MFMA 32x32 acc

#define MFMA(a, b, c) __builtin_amdgcn_mfma_f32_32x32x16_bf16(a, b, c, 0, 0, 0)

// float -> bf16 bits, round-to-nearest-even
__device__ __forceinline__ ushort f2bf(float f) {
    uint u = __float_as_uint(f);
    return (ushort)((u + 0x7FFFu + ((u >> 16) & 1u)) >> 16);
}
// split x ~= hi + lo (each bf16)
__device__ __forceinline__ void split2(float x, ushort& h, ushort& l) {
    h = f2bf(x);
    l = f2bf(x - __uint_as_float(((uint)h) << 16));
}
__device__ __forceinline__ void split4(float4 f, u64& h4, u64& l4) {
    ushort h0, h1, h2, h3, l0, l1, l2, l3;
    split2(f.x, h0, l0); split2(f.y, h1, l1);
    split2(f.z, h2, l2); split2(f.w, h3, l3);
    h4 = (u64)h0 | ((u64)h1 << 16) | ((u64)h2 << 32) | ((u64)h3 << 48);
    l4 = (u64)l0 | ((u64)l1 << 16) | ((u64)l2 << 32) | ((u64)l3 << 48);
}

union BF8 { u64 q[2]; ushort us[8]; s8v v; };

// swizzled ushort index: row stride 64 ushorts (128 B); XOR ushort-index
// bits 2..5 with row&15 -> frag reads are <=2-way conflicts.
__device__ __forceinline__ int swz(int row, int col) {
    return row * 64 + (col ^ ((row & 15) << 2));
}

// ---------------------------------------------------------------------------
// K1: RMSNorm  xn = x / max(||x||,eps) * g * sqrt(512).  One wave per token.
// ---------------------------------------------------------------------------
__global__ __launch_bounds__(256) void rmsnorm_k(const float* __restrict__ x,
                                                 const float* __restrict__ g,
                                                 float* __restrict__ xn) {
    const int wave = threadIdx.x >> 6;
    const int lane = threadIdx.x & 63;
    const size_t t = (size_t)blockIdx.x * 4 + wave;
    const float4* xp = (const float4*)(x + t * DIM + lane * 8);
    float4 v0 = xp[0], v1 = xp[1];
    float ss = v0.x * v0.x + v0.y * v0.y + v0.z * v0.z + v0.w * v0.w +
               v1.x * v1.x + v1.y * v1.y + v1.z * v1.z + v1.w * v1.w;
#pragma unroll
    for (int off = 32; off; off >>= 1) ss += __shfl_xor(ss, off);
    const float s = SQRT_DIM / fmaxf(sqrtf(ss), EPS_);
    const float4* gp = (const float4*)(g + lane * 8);
    float4 g0 = gp[0], g1 = gp[1];
    float4 o0, o1;
    o0.x = v0.x * s * g0.x; o0.y = v0.y * s * g0.y;
    o0.z = v0.z * s * g0.z; o0.w = v0.w * s * g0.w;
    o1.x = v1.x * s * g1.x; o1.y = v1.y * s * g1.y;
    o1.z = v1.z * s * g1.z; o1.w = v1.w * s * g1.w;
    float4* op = (float4*)(xn + t * DIM + lane * 8);
    op[0] = o0; op[1] = o1;
}

// ---------------------------------------------------------------------------
// K2: QKV GEMM  [16384,512] @ [512,1536], epilogue scatters to q/k/v [B,H,N,64].
// ---------------------------------------------------------------------------
__global__ __launch_bounds__(256) void qkv_gemm_k(const float* __restrict__ A,
                                                  const float* __restrict__ Bw,
                                                  float* __restrict__ qkv) {
    __shared__ float As[16][132];
    __shared__ float Bs[16][132];
    const int row0 = blockIdx.y * 128;
    const int col0 = blockIdx.x * 128;
    const int tid = threadIdx.x;
    const int ty = tid >> 4, tx = tid & 15;
    const int ar = tid >> 1, ak = (tid & 1) * 8;
    const int br = tid >> 4, bc = (tid & 15) * 8;
    float acc[8][8] = {};
    for (int k0 = 0; k0 < DIM; k0 += 16) {
        const float* ap = A + (size_t)(row0 + ar) * DIM + k0 + ak;
        float4 a0 = ((const float4*)ap)[0];
        float4 a1 = ((const float4*)ap)[1];
        const float* bp = Bw + (size_t)(k0 + br) * 1536 + col0 + bc;
        float4 b0 = ((const float4*)bp)[0];
        float4 b1 = ((const float4*)bp)[1];
        __syncthreads();
        As[ak + 0][ar] = a0.x; As[ak + 1][ar] = a0.y;
        As[ak + 2][ar] = a0.z; As[ak + 3][ar] = a0.w;
        As[ak + 4][ar] = a1.x; As[ak + 5][ar] = a1.y;
        As[ak + 6][ar] = a1.z; As[ak + 7][ar] = a1.w;
        *(float4*)&Bs[br][bc] = b0;
        *(float4*)&Bs[br][bc + 4] = b1;
        __syncthreads();
#pragma unroll 4
        for (int kk = 0; kk < 16; ++kk) {
            float4 aA = *(const float4*)&As[kk][ty * 8];
            float4 aB = *(const float4*)&As[kk][ty * 8 + 4];
            float4 bA = *(const float4*)&Bs[kk][tx * 8];
            float4 bB = *(const float4*)&Bs[kk][tx * 8 + 4];
            float av[8] = {aA.x, aA.y, aA.z, aA.w, aB.x, aB.y, aB.z, aB.w};
            float bv[8] = {bA.x, bA.y, bA.z, bA.w, bB.x, bB.y, bB.z, bB.w};
#pragma unroll
            for (int i = 0; i < 8; ++i)
#pragma unroll
                for (int j = 0; j < 8; ++j)
                    acc[i][j] = fmaf(av[i], bv[j], acc[i][j]);
        }
    }
    const int cbase = col0 + tx * 8;
    const int which = cbase / 512;
    const int h = (cbase % 512) / 64;
    const int d0 = cbase % 64;
    float* ob = qkv + (size_t)which * SZ;
#pragma unroll
    for (int i = 0; i < 8; ++i) {
        const int m = row0 + ty * 8 + i;
        const int b = m >> 11, n = m & 2047;
        float* p = ob + ((((size_t)b * HEADS + h) * N_ + n) * DHEAD + d0);
        *(float4*)p = make_float4(acc[i][0], acc[i][1], acc[i][2], acc[i][3]);
        *(float4*)(p + 4) = make_float4(acc[i][4], acc[i][5], acc[i][6], acc[i][7]);
    }
}

// ---------------------------------------------------------------------------
// K3: per-(b,h,n) l2norm over 64 dims, * scale.  One wave per row, in place.
// ---------------------------------------------------------------------------
__global__ __launch_bounds__(256) void qknorm_k(float* __restrict__ buf,
                                                const float* __restrict__ scale) {
    const int wave = threadIdx.x >> 6;
    const int lane = threadIdx.x & 63;
    const size_t row = (size_t)blockIdx.x * 4 + wave;
    float v = buf[row * DHEAD + lane];
    float ss = v * v;
#pragma unroll
    for (int off = 32; off; off >>= 1) ss += __shfl_xor(ss, off);
    const float inv = 1.0f / fmaxf(sqrtf(ss), EPS_);
    buf[row * DHEAD + lane] = v * inv * scale[lane];
}

// ---------------------------------------------------------------------------
// K4: MFMA attention.  QBLK=128 (4 waves x 32q strip), KVBLK=64.
// Split-bf16 (hi+lo) 3-MFMA emulation for both QK^T and PV (fp32-grade).
// S clamped to <=50 before exp: inactive when layout is correct (|S|<=8),
// guarantees finite output under ANY fragment-layout error (diagnostic).
// Rule-#18: lgkmcnt(0)+sched_barrier between per-wave P stores and reads.
// ---------------------------------------------------------------------------
__global__ __launch_bounds__(256, 2) void attn_k(const float* __restrict__ q,
                                                 const float* __restrict__ k,
                                                 const float* __restrict__ v,
                                                 float* __restrict__ o) {
    __shared__ __attribute__((aligned(16))) ushort Khi[64 * 64];
    __shared__ __attribute__((aligned(16))) ushort Klo[64 * 64];
    __shared__ __attribute__((aligned(16))) ushort Vthi[64 * 64];
    __shared__ __attribute__((aligned(16))) ushort Vtlo[64 * 64];
    __shared__ __attribute__((aligned(16))) ushort Pbuf[4][2][32 * 64];

    const int bh = blockIdx.y;
    const int q0 = blockIdx.x * 128;
    const int tid = threadIdx.x;
    const int ws = tid >> 6;
    const int lo5 = tid & 31;         // lane & 31
    const int hi5 = (tid & 63) >> 5;  // lane >> 5
    const size_t base = (size_t)bh * (N_ * DHEAD);
    const float* kbh = k + base;
    const float* vbh = v + base;

    // ---- Q fragments in registers, scaled by 8 (softmax scale) ----
    const int qrow0 = q0 + ws * 32;
    const int qrow = qrow0 + lo5;
    s8v qh[4], ql[4];
#pragma unroll
    for (int s = 0; s < 4; ++s) {
        const float* qp = q + base + (size_t)qrow * DHEAD + 16 * s + 8 * hi5;
        float4 a = *(const float4*)qp;
        float4 b = *(const float4*)(qp + 4);
        float qv[8] = {a.x, a.y, a.z, a.w, b.x, b.y, b.z, b.w};
        BF8 hh, ll;
#pragma unroll
        for (int j = 0; j < 8; ++j) {
            ushort h, l;
            split2(qv[j] * SCALE_, h, l);
            hh.us[j] = h; ll.us[j] = l;
        }
        qh[s] = hh.v; ql[s] = ll.v;
    }

    f16v o0 = {0,0,0,0,0,0,0,0,0,0,0,0,0,0,0,0};
    f16v o1 = {0,0,0,0,0,0,0,0,0,0,0,0,0,0,0,0};
    float dsum[16];
#pragma unroll
    for (int r = 0; r < 16; ++r) dsum[r] = 0.0f;

    ushort* Phw = Pbuf[ws][0];
    ushort* Plw = Pbuf[ws][1];

    // prefetch tile 0
    float4 kreg[4], vreg[4];
#pragma unroll
    for (int u = 0; u < 4; ++u) {
        const int f = tid + 256 * u;                 // float4 index in 64x64 tile
        kreg[u] = *(const float4*)(kbh + (size_t)f * 4);
        vreg[u] = *(const float4*)(vbh + (size_t)f * 4);
    }

    for (int kt = 0; kt < N_ / 64; ++kt) {
        __syncthreads();   // all waves done reading K/Vt of prev tile
        // ---- stage K (hi/lo) and V^T (hi/lo) into LDS ----
#pragma unroll
        for (int u = 0; u < 4; ++u) {
            const int f = tid + 256 * u;
            const int key = f >> 4;
            const int dd = (f & 15) * 4;
            u64 kh4, kl4;
            split4(kreg[u], kh4, kl4);
            *(u64*)&Khi[swz(key, dd)] = kh4;
            *(u64*)&Klo[swz(key, dd)] = kl4;
            float vv[4] = {vreg[u].x, vreg[u].y, vreg[u].z, vreg[u].w};
#pragma unroll
            for (int c = 0; c < 4; ++c) {
                ushort vh, vl;
                split2(vv[c], vh, vl);
                const int idx = swz(dd + c, key);
                Vthi[idx] = vh; Vtlo[idx] = vl;
            }
        }
        __syncthreads();
        // ---- prefetch next tile ----
        if (kt + 1 < N_ / 64) {
#pragma unroll
            for (int u = 0; u < 4; ++u) {
                const int f = tid + 256 * u;
                const size_t off = (size_t)(kt + 1) * (64 * DHEAD) + (size_t)f * 4;
                kreg[u] = *(const float4*)(kbh + off);
                vreg[u] = *(const float4*)(vbh + off);
            }
        }
        // ---- S = (8 Q) K^T via 3-term split MFMA ----
        f16v s0 = {0,0,0,0,0,0,0,0,0,0,0,0,0,0,0,0};
        f16v s1 = {0,0,0,0,0,0,0,0,0,0,0,0,0,0,0,0};
#pragma unroll
        for (int s = 0; s < 4; ++s) {
            const int d0 = 16 * s + 8 * hi5;
            BF8 b0h, b0l, b1h, b1l;
            b0h.q[0] = *(const u64*)&Khi[swz(lo5, d0)];
            b0h.q[1] = *(const u64*)&Khi[swz(lo5, d0 + 4)];
            b0l.q[0] = *(const u64*)&Klo[swz(lo5, d0)];
            b0l.q[1] = *(const u64*)&Klo[swz(lo5, d0 + 4)];
            b1h.q[0] = *(const u64*)&Khi[swz(32 + lo5, d0)];
            b1h.q[1] = *(const u64*)&Khi[swz(32 + lo5, d0 + 4)];
            b1l.q[0] = *(const u64*)&Klo[swz(32 + lo5, d0)];
            b1l.q[1] = *(const u64*)&Klo[swz(32 + lo5, d0 + 4)];
            s0 = MFMA(qh[s], b0h.v, s0);
            s1 = MFMA(qh[s], b1h.v, s1);
            s0 = MFMA(ql[s], b0h.v, s0);
            s1 = MFMA(ql[s], b1h.v, s1);
            s0 = MFMA(qh[s], b0l.v, s0);
            s1 = MFMA(qh[s], b1l.v, s1);
        }
        // ---- P = exp(min(S,50)); accumulate denom; store P (hi/lo) to LDS ----
#pragma unroll
        for (int r = 0; r < 16; ++r) {
            const float p0 = __expf(fminf(s0[r], 50.0f));
            const float p1 = __expf(fminf(s1[r], 50.0f));
            dsum[r] += p0 + p1;
            const int qr = (r & 3) + 8 * (r >> 2) + 4 * hi5;   // C/D row map
            ushort h, l;
            split2(p0, h, l);
            int idx = swz(qr, lo5);
            Phw[idx] = h; Plw[idx] = l;
            split2(p1, h, l);
            idx = swz(qr, 32 + lo5);
            Phw[idx] = h; Plw[idx] = l;
        }
        // rule #18: drain LDS writes, pin scheduler — P reads below must not
        // be hoisted above the per-wave P stores (no barrier in between).
        asm volatile("s_waitcnt lgkmcnt(0)" ::: "memory");
        __builtin_amdgcn_sched_barrier(0);
        // ---- O += P V via 3-term split MFMA (per-wave P, no barrier) ----
#pragma unroll
        for (int s = 0; s < 4; ++s) {
            const int koff = 16 * s + 8 * hi5;
            BF8 pah, pal, v0h, v0l, v1h, v1l;
            pah.q[0] = *(const u64*)&Phw[swz(lo5, koff)];
            pah.q[1] = *(const u64*)&Phw[swz(lo5, koff + 4)];
            pal.q[0] = *(const u64*)&Plw[swz(lo5, koff)];
            pal.q[1] = *(const u64*)&Plw[swz(lo5, koff + 4)];
            v0h.q[0] = *(const u64*)&Vthi[swz(lo5, koff)];
            v0h.q[1] = *(const u64*)&Vthi[swz(lo5, koff + 4)];
            v0l.q[0] = *(const u64*)&Vtlo[swz(lo5, koff)];
            v0l.q[1] = *(const u64*)&Vtlo[swz(lo5, koff + 4)];
            v1h.q[0] = *(const u64*)&Vthi[swz(32 + lo5, koff)];
            v1h.q[1] = *(const u64*)&Vthi[swz(32 + lo5, koff + 4)];
            v1l.q[0] = *(const u64*)&Vtlo[swz(32 + lo5, koff)];
            v1l.q[1] = *(const u64*)&Vtlo[swz(32 + lo5, koff + 4)];
            o0 = MFMA(pah.v, v0h.v, o0);
            o1 = MFMA(pah.v, v1h.v, o1);
            o0 = MFMA(pal.v, v0h.v, o0);
            o1 = MFMA(pal.v, v1h.v, o1);
            o0 = MFMA(pah.v, v0l.v, o0);
            o1 = MFMA(pah.v, v1l.v, o1);
        }
    }
    // ---- reduce denominators across the 32 key-columns ----
#pragma unroll
    for (int r = 0; r < 16; ++r) {
#pragma unroll
        for (int off = 1; off < 32; off <<= 1)
            dsum[r] += __shfl_xor(dsum[r], off);
    }
    // ---- write O / denom ----
    float* obh = o + base;
#pragma unroll
    for (int r = 0; r < 16; ++r) {
        const int qr = (r & 3) + 8 * (r >> 2) + 4 * hi5;
        const float inv = 1.0f / dsum[r];
        obh[(size_t)(qrow0 + qr) * DHEAD + lo5]      = o0[r] * inv;
        obh[(size_t)(qrow0 + qr) * DHEAD + 32 + lo5] = o1[r] * inv;
    }
}

// ---------------------------------------------------------------------------
// K5: out GEMM  [16384,512] @ [512,512] -> d_out, A gathered from [B,H,N,64].
// ---------------------------------------------------------------------------
__global__ __launch_bounds__(256) void out_gemm_k(const float* __restrict__ Ain,
                                                  const float* __restrict__ Bw,
                                                  float* __restrict__ C) {
    __shared__ float As[16][132];
    __shared__ float Bs[16][132];
    const int row0 = blockIdx.y * 128;
    const int col0 = blockIdx.x * 128;
    const int tid = threadIdx.x;
    const int ty = tid >> 4, tx = tid & 15;
    const int ar = tid >> 1, ak = (tid & 1) * 8;
    const int br = tid >> 4, bc = (tid & 15) * 8;
    const int m_ = row0 + ar;
    const int ab = m_ >> 11, an = m_ & 2047;
    float acc[8][8] = {};
    for (int k0 = 0; k0 < DIM; k0 += 16) {
        const int c0 = k0 + ak;
        const int h = c0 >> 6, d0 = c0 & 63;
        const float* ap = Ain + ((((size_t)ab * HEADS + h) * N_ + an) * DHEAD + d0);
        float4 a0 = ((const float4*)ap)[0];
        float4 a1 = ((const float4*)ap)[1];
        const float* bp = Bw + (size_t)(k0 + br) * DIM + col0 + bc;
        float4 b0 = ((const float4*)bp)[0];
        float4 b1 = ((const float4*)bp)[1];
        __syncthreads();
        As[ak + 0][ar] = a0.x; As[ak + 1][ar] = a0.y;
        As[ak + 2][ar] = a0.z; As[ak + 3][ar] = a0.w;
        As[ak + 4][ar] = a1.x; As[ak + 5][ar] = a1.y;
        As[ak + 6][ar] = a1.z; As[ak + 7][ar] = a1.w;
        *(float4*)&Bs[br][bc] = b0;
        *(float4*)&Bs[br][bc + 4] = b1;
        __syncthreads();
#pragma unroll 4
        for (int kk = 0; kk < 16; ++kk) {
            float4 aA = *(const float4*)&As[kk][ty * 8];
            float4 aB = *(const float4*)&As[kk][ty * 8 + 4];
            float4 bA = *(const float4*)&Bs[kk][tx * 8];
            float4 bB = *(const float4*)&Bs[kk][tx * 8 + 4];
            float av[8] = {aA.x, aA.y, aA.z, aA.w, aB.x, aB.y, aB.z, aB.w};
            float bv[8] = {bA.x, bA.y, bA.z, bA.w, bB.x, bB.y, bB.z, bB.w};
#pragma unroll
            for (int i = 0; i < 8; ++i)
#pragma unroll
                for (int j = 0; j < 8; ++j)
                    acc[i][j] = fmaf(av[i], bv[j], acc[i][j]);
        }
    }
#pragma unroll
    for (int i = 0; i < 8; ++i) {
        const int m = row0 + ty * 8 + i;
        float* p = C + (size_t)m * DIM + col0 + tx * 8;
        *(float4*)p = make_float4(acc[i][0], acc[i][1], acc[i][2], acc[i][3]);
        *(float4*)(p + 4) = make_float4(acc[i][4], acc[i][5], acc[i][6], acc[i][7]);
    }
}

// ---------------------------------------------------------------------------
extern "C" void kernel_launch(void* const* d_in, const int* in_sizes, int n_in,
                              void* d_out, int out_size, void* d_ws, size_t ws_size,
                              hipStream_t stream) {
    const float* x       = (const float*)d_in[0];
    const float* g       = (const float*)d_in[1];
    const float* w_qkv   = (const float*)d_in[2];
    const float* q_scale = (const float*)d_in[3];
    const float* k_scale = (const float*)d_in[4];
    const float* w_out   = (const float*)d_in[5];
    float* out = (float*)d_out;
    float* ws  = (float*)d_ws;

    if (ws_size < 4 * SZ * sizeof(float)) return;

    float* xn = ws;
    float* qb = ws + SZ;
    float* kb = ws + 2 * SZ;
    float* vb = ws + 3 * SZ;
    float* ao = ws;             // reuses xn slot

    rmsnorm_k<<<TOKENS / 4, 256, 0, stream>>>(x, g, xn);
    qkv_gemm_k<<<dim3(1536 / 128, TOKENS / 128), 256, 0, stream>>>(xn, w_qkv, qb);
    qknorm_k<<<(TOKENS * HEADS) / 4, 256, 0, stream>>>(qb, q_scale);
    qknorm_k<<<(TOKENS * HEADS) / 4, 256, 0, stream>>>(kb, k_scale);
    attn_k<<<dim3(N_ / 128, B_ * HEADS), 256, 0, stream>>>(qb, kb, vb, ao);
    out_gemm_k<<<dim3(DIM / 128, TOKENS / 128), 256, 0, stream>>>(ao, w_out, out);
}

// Round 5
// 624.281 us; speedup vs baseline: 2.5488x; 1.4784x over previous
//
#include <hip/hip_runtime.h>
#include <math.h>

#define B_ 8
#define N_ 2048
#define DIM 512
#define HEADS 8
#define DHEAD 64
#define TOKENS (B_ * N_)                 // 16384
#define SZ ((size_t)TOKENS * DIM)        // 8388608 floats per [B,*,512]-sized buffer
#define SCALE_ 8.0f
#define EPS_ 1e-12f
#define SQRT_DIM 22.62741699796952f      // sqrt(512)

typedef unsigned long long u64;
typedef __attribute__((ext_vector_type(8))) short s8v;     // 8 bf16 (4 VGPR)
typedef __attribute__((ext_vector_type(16))) float f16v;   // MFMA 32x32 acc

#define MFMA(a, b, c) __builtin_amdgcn_mfma_f32_32x32x16_bf16(a, b, c, 0, 0, 0)

// float -> bf16 bits, round-to-nearest-even
__device__ __forceinline__ ushort f2bf(float f) {
    uint u = __float_as_uint(f);
    return (ushort)((u + 0x7FFFu + ((u >> 16) & 1u)) >> 16);
}
__device__ __forceinline__ float bf2f(ushort h) {
    return __uint_as_float(((uint)h) << 16);
}
// split x ~= hi + lo (each bf16)
__device__ __forceinline__ void split2(float x, ushort& h, ushort& l) {
    h = f2bf(x);
    l = f2bf(x - bf2f(h));
}
__device__ __forceinline__ void split4(float4 f, u64& h4, u64& l4) {
    ushort h0, h1, h2, h3, l0, l1, l2, l3;
    split2(f.x, h0, l0); split2(f.y, h1, l1);
    split2(f.z, h2, l2); split2(f.w, h3, l3);
    h4 = (u64)h0 | ((u64)h1 << 16) | ((u64)h2 << 32) | ((u64)h3 << 48);
    l4 = (u64)l0 | ((u64)l1 << 16) | ((u64)l2 << 32) | ((u64)l3 << 48);
}

union BF8 { u64 q[2]; ushort us[8]; s8v v; };

// attn LDS swizzle: row stride 64 ushorts; XOR ushort-index bits 2..5 with
// row&15 -> frag reads are <=2-way conflicts.
__device__ __forceinline__ int swz(int row, int col) {
    return row * 64 + (col ^ ((row & 15) << 2));
}

// ---------------------------------------------------------------------------
// K0: transpose + split  W[K][N] f32  ->  WT_hi / WT_lo [N][K] bf16 planes.
// ---------------------------------------------------------------------------
__global__ __launch_bounds__(256) void split_w_k(const float* __restrict__ W,
                                                 ushort* __restrict__ WThi,
                                                 ushort* __restrict__ WTlo,
                                                 int K, int N) {
    __shared__ float T[32][33];
    const int k0 = blockIdx.y * 32, n0 = blockIdx.x * 32;
    const int tr = threadIdx.x >> 5;      // 0..7
    const int tc = threadIdx.x & 31;
#pragma unroll
    for (int i = 0; i < 4; ++i)
        T[tr + 8 * i][tc] = W[(size_t)(k0 + tr + 8 * i) * N + n0 + tc];
    __syncthreads();
#pragma unroll
    for (int i = 0; i < 4; ++i) {
        const int n = tr + 8 * i;
        ushort h, l;
        split2(T[tc][n], h, l);
        WThi[(size_t)(n0 + n) * K + k0 + tc] = h;
        WTlo[(size_t)(n0 + n) * K + k0 + tc] = l;
    }
}

// ---------------------------------------------------------------------------
// K1: RMSNorm -> hi/lo bf16 planes [token][512].
// ---------------------------------------------------------------------------
__global__ __launch_bounds__(256) void rmsnorm_k(const float* __restrict__ x,
                                                 const float* __restrict__ g,
                                                 ushort* __restrict__ xnhi,
                                                 ushort* __restrict__ xnlo) {
    const int wave = threadIdx.x >> 6;
    const int lane = threadIdx.x & 63;
    const size_t t = (size_t)blockIdx.x * 4 + wave;
    const float4* xp = (const float4*)(x + t * DIM + lane * 8);
    float4 v0 = xp[0], v1 = xp[1];
    float ss = v0.x * v0.x + v0.y * v0.y + v0.z * v0.z + v0.w * v0.w +
               v1.x * v1.x + v1.y * v1.y + v1.z * v1.z + v1.w * v1.w;
#pragma unroll
    for (int off = 32; off; off >>= 1) ss += __shfl_xor(ss, off);
    const float s = SQRT_DIM / fmaxf(sqrtf(ss), EPS_);
    const float4* gp = (const float4*)(g + lane * 8);
    float4 g0 = gp[0], g1 = gp[1];
    float ov[8] = {v0.x * s * g0.x, v0.y * s * g0.y, v0.z * s * g0.z,
                   v0.w * s * g0.w, v1.x * s * g1.x, v1.y * s * g1.y,
                   v1.z * s * g1.z, v1.w * s * g1.w};
    ushort h[8], l[8];
#pragma unroll
    for (int j = 0; j < 8; ++j) split2(ov[j], h[j], l[j]);
    uint4 H, L;
    H.x = (uint)h[0] | ((uint)h[1] << 16); H.y = (uint)h[2] | ((uint)h[3] << 16);
    H.z = (uint)h[4] | ((uint)h[5] << 16); H.w = (uint)h[6] | ((uint)h[7] << 16);
    L.x = (uint)l[0] | ((uint)l[1] << 16); L.y = (uint)l[2] | ((uint)l[3] << 16);
    L.z = (uint)l[4] | ((uint)l[5] << 16); L.w = (uint)l[6] | ((uint)l[7] << 16);
    *(uint4*)(xnhi + t * DIM + lane * 8) = H;
    *(uint4*)(xnlo + t * DIM + lane * 8) = L;
}

// ---------------------------------------------------------------------------
// K2: split-bf16 MFMA GEMM  [16384,512] @ WT[N][512] planes.
// Tile 128x128, BK=32, 4 waves (2x2), 3-term split (ah*bh + al*bh + ah*bl).
// MODE 0: N=1536, epilogue scatters to q/k/v [B,H,N,64] f32.
// MODE 1: N=512,  plain f32 store.
// LDS rows padded to 36 ushorts -> frag reads 2 lanes/bank (free).
// ---------------------------------------------------------------------------
template <int MODE>
__global__ __launch_bounds__(256, 2) void mfma_gemm_k(
    const ushort* __restrict__ Ahi, const ushort* __restrict__ Alo,
    const ushort* __restrict__ Bhi, const ushort* __restrict__ Blo,
    float* __restrict__ out) {
    __shared__ __attribute__((aligned(16))) ushort Ah[128 * 36];
    __shared__ __attribute__((aligned(16))) ushort Al[128 * 36];
    __shared__ __attribute__((aligned(16))) ushort Bh[128 * 36];
    __shared__ __attribute__((aligned(16))) ushort Bl[128 * 36];
    const int row0 = blockIdx.y * 128;
    const int col0 = blockIdx.x * 128;
    const int tid = threadIdx.x;
    const int wv = tid >> 6;
    const int wy = wv >> 1, wx = wv & 1;
    const int lo5 = tid & 31;
    const int hi5 = (tid & 63) >> 5;
    const int sr = tid >> 1;              // staging row 0..127
    const int sh = (tid & 1) * 16;        // staging k-offset (16 ushorts)

    f16v acc[2][2];
#pragma unroll
    for (int i = 0; i < 2; ++i)
#pragma unroll
        for (int j = 0; j < 2; ++j)
#pragma unroll
            for (int r = 0; r < 16; ++r) acc[i][j][r] = 0.0f;

    uint4 ra[2][2], rb[2][2];   // [plane][chunk]
    const size_t abase = (size_t)(row0 + sr) * DIM + sh;
    const size_t bbase = (size_t)(col0 + sr) * DIM + sh;
    // preload k0 = 0
    ra[0][0] = *(const uint4*)(Ahi + abase);     ra[0][1] = *(const uint4*)(Ahi + abase + 8);
    ra[1][0] = *(const uint4*)(Alo + abase);     ra[1][1] = *(const uint4*)(Alo + abase + 8);
    rb[0][0] = *(const uint4*)(Bhi + bbase);     rb[0][1] = *(const uint4*)(Bhi + bbase + 8);
    rb[1][0] = *(const uint4*)(Blo + bbase);     rb[1][1] = *(const uint4*)(Blo + bbase + 8);

    const int sbase = sr * 36 + sh;
    for (int k0 = 0; k0 < DIM; k0 += 32) {
        __syncthreads();
        *(uint2*)&Ah[sbase]      = make_uint2(ra[0][0].x, ra[0][0].y);
        *(uint2*)&Ah[sbase + 4]  = make_uint2(ra[0][0].z, ra[0][0].w);
        *(uint2*)&Ah[sbase + 8]  = make_uint2(ra[0][1].x, ra[0][1].y);
        *(uint2*)&Ah[sbase + 12] = make_uint2(ra[0][1].z, ra[0][1].w);
        *(uint2*)&Al[sbase]      = make_uint2(ra[1][0].x, ra[1][0].y);
        *(uint2*)&Al[sbase + 4]  = make_uint2(ra[1][0].z, ra[1][0].w);
        *(uint2*)&Al[sbase + 8]  = make_uint2(ra[1][1].x, ra[1][1].y);
        *(uint2*)&Al[sbase + 12] = make_uint2(ra[1][1].z, ra[1][1].w);
        *(uint2*)&Bh[sbase]      = make_uint2(rb[0][0].x, rb[0][0].y);
        *(uint2*)&Bh[sbase + 4]  = make_uint2(rb[0][0].z, rb[0][0].w);
        *(uint2*)&Bh[sbase + 8]  = make_uint2(rb[0][1].x, rb[0][1].y);
        *(uint2*)&Bh[sbase + 12] = make_uint2(rb[0][1].z, rb[0][1].w);
        *(uint2*)&Bl[sbase]      = make_uint2(rb[1][0].x, rb[1][0].y);
        *(uint2*)&Bl[sbase + 4]  = make_uint2(rb[1][0].z, rb[1][0].w);
        *(uint2*)&Bl[sbase + 8]  = make_uint2(rb[1][1].x, rb[1][1].y);
        *(uint2*)&Bl[sbase + 12] = make_uint2(rb[1][1].z, rb[1][1].w);
        __syncthreads();
        if (k0 + 32 < DIM) {
            const size_t a2 = abase + k0 + 32, b2 = bbase + k0 + 32;
            ra[0][0] = *(const uint4*)(Ahi + a2); ra[0][1] = *(const uint4*)(Ahi + a2 + 8);
            ra[1][0] = *(const uint4*)(Alo + a2); ra[1][1] = *(const uint4*)(Alo + a2 + 8);
            rb[0][0] = *(const uint4*)(Bhi + b2); rb[0][1] = *(const uint4*)(Bhi + b2 + 8);
            rb[1][0] = *(const uint4*)(Blo + b2); rb[1][1] = *(const uint4*)(Blo + b2 + 8);
        }
#pragma unroll
        for (int ks = 0; ks < 2; ++ks) {
            s8v a_h[2], a_l[2], b_h[2], b_l[2];
#pragma unroll
            for (int rt = 0; rt < 2; ++rt) {
                const int off = (wy * 64 + rt * 32 + lo5) * 36 + ks * 16 + 8 * hi5;
                BF8 th, tl;
                th.q[0] = *(const u64*)&Ah[off]; th.q[1] = *(const u64*)&Ah[off + 4];
                tl.q[0] = *(const u64*)&Al[off]; tl.q[1] = *(const u64*)&Al[off + 4];
                a_h[rt] = th.v; a_l[rt] = tl.v;
            }
#pragma unroll
            for (int ct = 0; ct < 2; ++ct) {
                const int off = (wx * 64 + ct * 32 + lo5) * 36 + ks * 16 + 8 * hi5;
                BF8 th, tl;
                th.q[0] = *(const u64*)&Bh[off]; th.q[1] = *(const u64*)&Bh[off + 4];
                tl.q[0] = *(const u64*)&Bl[off]; tl.q[1] = *(const u64*)&Bl[off + 4];
                b_h[ct] = th.v; b_l[ct] = tl.v;
            }
#pragma unroll
            for (int rt = 0; rt < 2; ++rt)
#pragma unroll
                for (int ct = 0; ct < 2; ++ct) {
                    acc[rt][ct] = MFMA(a_h[rt], b_h[ct], acc[rt][ct]);
                    acc[rt][ct] = MFMA(a_l[rt], b_h[ct], acc[rt][ct]);
                    acc[rt][ct] = MFMA(a_h[rt], b_l[ct], acc[rt][ct]);
                }
        }
    }
    // epilogue
#pragma unroll
    for (int rt = 0; rt < 2; ++rt)
#pragma unroll
        for (int ct = 0; ct < 2; ++ct) {
            const int c = col0 + wx * 64 + ct * 32 + lo5;
            if (MODE == 0) {
                const int which = c / 512;
                const int within = c % 512;
                const int h = within >> 6, d = within & 63;
                float* ob = out + (size_t)which * SZ;
#pragma unroll
                for (int r = 0; r < 16; ++r) {
                    const int m = row0 + wy * 64 + rt * 32 + (r & 3) + 8 * (r >> 2) + 4 * hi5;
                    const int b = m >> 11, n = m & 2047;
                    ob[(((size_t)b * HEADS + h) * N_ + n) * DHEAD + d] = acc[rt][ct][r];
                }
            } else {
#pragma unroll
                for (int r = 0; r < 16; ++r) {
                    const int m = row0 + wy * 64 + rt * 32 + (r & 3) + 8 * (r >> 2) + 4 * hi5;
                    out[(size_t)m * DIM + c] = acc[rt][ct][r];
                }
            }
        }
}

// ---------------------------------------------------------------------------
// K3: per-(b,h,n) l2norm over 64 dims, * scale.  One wave per row, in place.
// ---------------------------------------------------------------------------
__global__ __launch_bounds__(256) void qknorm_k(float* __restrict__ buf,
                                                const float* __restrict__ scale) {
    const int wave = threadIdx.x >> 6;
    const int lane = threadIdx.x & 63;
    const size_t row = (size_t)blockIdx.x * 4 + wave;
    float v = buf[row * DHEAD + lane];
    float ss = v * v;
#pragma unroll
    for (int off = 32; off; off >>= 1) ss += __shfl_xor(ss, off);
    const float inv = 1.0f / fmaxf(sqrtf(ss), EPS_);
    buf[row * DHEAD + lane] = v * inv * scale[lane];
}

// ---------------------------------------------------------------------------
// K4: MFMA attention.  QBLK=128 (4 waves x 32q strip), KVBLK=64.
// QK^T: 3-term split (precision-critical pre-exp).  P: single bf16 plane;
// denominator accumulated from ROUNDED P (numerator/denominator share
// weights -> common-mode error cancels).  PV: pah x {vhi, vlo} = 4 MFMA/s.
// O written as hi/lo bf16 planes [token][hidden] for the MFMA out-GEMM.
// ---------------------------------------------------------------------------
__global__ __launch_bounds__(256, 2) void attn_k(const float* __restrict__ q,
                                                 const float* __restrict__ k,
                                                 const float* __restrict__ v,
                                                 ushort* __restrict__ Ohi,
                                                 ushort* __restrict__ Olo) {
    __shared__ __attribute__((aligned(16))) ushort Khi[64 * 64];
    __shared__ __attribute__((aligned(16))) ushort Klo[64 * 64];
    __shared__ __attribute__((aligned(16))) ushort Vthi[64 * 64];
    __shared__ __attribute__((aligned(16))) ushort Vtlo[64 * 64];
    __shared__ __attribute__((aligned(16))) ushort Pbuf[4][32 * 64];

    const int bh = blockIdx.y;
    const int q0 = blockIdx.x * 128;
    const int tid = threadIdx.x;
    const int ws = tid >> 6;
    const int lo5 = tid & 31;
    const int hi5 = (tid & 63) >> 5;
    const size_t base = (size_t)bh * (N_ * DHEAD);
    const float* kbh = k + base;
    const float* vbh = v + base;

    // ---- Q fragments in registers, scaled by 8 (softmax scale) ----
    const int qrow0 = q0 + ws * 32;
    const int qrow = qrow0 + lo5;
    s8v qh[4], ql[4];
#pragma unroll
    for (int s = 0; s < 4; ++s) {
        const float* qp = q + base + (size_t)qrow * DHEAD + 16 * s + 8 * hi5;
        float4 a = *(const float4*)qp;
        float4 b = *(const float4*)(qp + 4);
        float qv[8] = {a.x, a.y, a.z, a.w, b.x, b.y, b.z, b.w};
        BF8 hh, ll;
#pragma unroll
        for (int j = 0; j < 8; ++j) {
            ushort h, l;
            split2(qv[j] * SCALE_, h, l);
            hh.us[j] = h; ll.us[j] = l;
        }
        qh[s] = hh.v; ql[s] = ll.v;
    }

    f16v o0 = {0,0,0,0,0,0,0,0,0,0,0,0,0,0,0,0};
    f16v o1 = {0,0,0,0,0,0,0,0,0,0,0,0,0,0,0,0};
    float dsum[16];
#pragma unroll
    for (int r = 0; r < 16; ++r) dsum[r] = 0.0f;

    ushort* Pw = Pbuf[ws];

    // prefetch tile 0
    float4 kreg[4], vreg[4];
#pragma unroll
    for (int u = 0; u < 4; ++u) {
        const int f = tid + 256 * u;                 // float4 index in 64x64 tile
        kreg[u] = *(const float4*)(kbh + (size_t)f * 4);
        vreg[u] = *(const float4*)(vbh + (size_t)f * 4);
    }

    for (int kt = 0; kt < N_ / 64; ++kt) {
        __syncthreads();   // all waves done reading K/Vt of prev tile
        // ---- stage K (hi/lo) and V^T (hi/lo) into LDS ----
#pragma unroll
        for (int u = 0; u < 4; ++u) {
            const int f = tid + 256 * u;
            const int key = f >> 4;
            const int dd = (f & 15) * 4;
            u64 kh4, kl4;
            split4(kreg[u], kh4, kl4);
            *(u64*)&Khi[swz(key, dd)] = kh4;
            *(u64*)&Klo[swz(key, dd)] = kl4;
            float vv[4] = {vreg[u].x, vreg[u].y, vreg[u].z, vreg[u].w};
#pragma unroll
            for (int c = 0; c < 4; ++c) {
                ushort vh, vl;
                split2(vv[c], vh, vl);
                const int idx = swz(dd + c, key);
                Vthi[idx] = vh; Vtlo[idx] = vl;
            }
        }
        __syncthreads();
        // ---- prefetch next tile ----
        if (kt + 1 < N_ / 64) {
#pragma unroll
            for (int u = 0; u < 4; ++u) {
                const int f = tid + 256 * u;
                const size_t off = (size_t)(kt + 1) * (64 * DHEAD) + (size_t)f * 4;
                kreg[u] = *(const float4*)(kbh + off);
                vreg[u] = *(const float4*)(vbh + off);
            }
        }
        // ---- S = (8 Q) K^T via 3-term split MFMA ----
        f16v s0 = {0,0,0,0,0,0,0,0,0,0,0,0,0,0,0,0};
        f16v s1 = {0,0,0,0,0,0,0,0,0,0,0,0,0,0,0,0};
#pragma unroll
        for (int s = 0; s < 4; ++s) {
            const int d0 = 16 * s + 8 * hi5;
            BF8 b0h, b0l, b1h, b1l;
            b0h.q[0] = *(const u64*)&Khi[swz(lo5, d0)];
            b0h.q[1] = *(const u64*)&Khi[swz(lo5, d0 + 4)];
            b0l.q[0] = *(const u64*)&Klo[swz(lo5, d0)];
            b0l.q[1] = *(const u64*)&Klo[swz(lo5, d0 + 4)];
            b1h.q[0] = *(const u64*)&Khi[swz(32 + lo5, d0)];
            b1h.q[1] = *(const u64*)&Khi[swz(32 + lo5, d0 + 4)];
            b1l.q[0] = *(const u64*)&Klo[swz(32 + lo5, d0)];
            b1l.q[1] = *(const u64*)&Klo[swz(32 + lo5, d0 + 4)];
            s0 = MFMA(qh[s], b0h.v, s0);
            s1 = MFMA(qh[s], b1h.v, s1);
            s0 = MFMA(ql[s], b0h.v, s0);
            s1 = MFMA(ql[s], b1h.v, s1);
            s0 = MFMA(qh[s], b0l.v, s0);
            s1 = MFMA(qh[s], b1l.v, s1);
        }
        // ---- P = bf16(exp(min(S,50))); denom from rounded P; store ----
#pragma unroll
        for (int r = 0; r < 16; ++r) {
            const float p0 = __expf(fminf(s0[r], 50.0f));
            const float p1 = __expf(fminf(s1[r], 50.0f));
            const ushort h0 = f2bf(p0);
            const ushort h1 = f2bf(p1);
            dsum[r] += bf2f(h0) + bf2f(h1);
            const int qr = (r & 3) + 8 * (r >> 2) + 4 * hi5;   // C/D row map
            Pw[swz(qr, lo5)] = h0;
            Pw[swz(qr, 32 + lo5)] = h1;
        }
        // rule #18: drain LDS writes, pin scheduler — P reads below must not
        // be hoisted above the per-wave P stores (no barrier in between).
        asm volatile("s_waitcnt lgkmcnt(0)" ::: "memory");
        __builtin_amdgcn_sched_barrier(0);
        // ---- O += P V  (pah x {v hi, v lo}) ----
#pragma unroll
        for (int s = 0; s < 4; ++s) {
            const int koff = 16 * s + 8 * hi5;
            BF8 pah, v0h, v0l, v1h, v1l;
            pah.q[0] = *(const u64*)&Pw[swz(lo5, koff)];
            pah.q[1] = *(const u64*)&Pw[swz(lo5, koff + 4)];
            v0h.q[0] = *(const u64*)&Vthi[swz(lo5, koff)];
            v0h.q[1] = *(const u64*)&Vthi[swz(lo5, koff + 4)];
            v0l.q[0] = *(const u64*)&Vtlo[swz(lo5, koff)];
            v0l.q[1] = *(const u64*)&Vtlo[swz(lo5, koff + 4)];
            v1h.q[0] = *(const u64*)&Vthi[swz(32 + lo5, koff)];
            v1h.q[1] = *(const u64*)&Vthi[swz(32 + lo5, koff + 4)];
            v1l.q[0] = *(const u64*)&Vtlo[swz(32 + lo5, koff)];
            v1l.q[1] = *(const u64*)&Vtlo[swz(32 + lo5, koff + 4)];
            o0 = MFMA(pah.v, v0h.v, o0);
            o1 = MFMA(pah.v, v1h.v, o1);
            o0 = MFMA(pah.v, v0l.v, o0);
            o1 = MFMA(pah.v, v1l.v, o1);
        }
    }
    // ---- reduce denominators across the 32 key-columns ----
#pragma unroll
    for (int r = 0; r < 16; ++r) {
#pragma unroll
        for (int off = 1; off < 32; off <<= 1)
            dsum[r] += __shfl_xor(dsum[r], off);
    }
    // ---- write O / denom as hi/lo planes [token][hidden] ----
    const int b = bh >> 3, hh = bh & 7;
#pragma unroll
    for (int r = 0; r < 16; ++r) {
        const int qr = (r & 3) + 8 * (r >> 2) + 4 * hi5;
        const float inv = 1.0f / dsum[r];
        const size_t rowb = ((size_t)b * N_ + qrow0 + qr) * DIM + hh * DHEAD;
        ushort h, l;
        split2(o0[r] * inv, h, l);
        Ohi[rowb + lo5] = h;      Olo[rowb + lo5] = l;
        split2(o1[r] * inv, h, l);
        Ohi[rowb + 32 + lo5] = h; Olo[rowb + 32 + lo5] = l;
    }
}

// ---------------------------------------------------------------------------
extern "C" void kernel_launch(void* const* d_in, const int* in_sizes, int n_in,
                              void* d_out, int out_size, void* d_ws, size_t ws_size,
                              hipStream_t stream) {
    const float* x       = (const float*)d_in[0];
    const float* g       = (const float*)d_in[1];
    const float* w_qkv   = (const float*)d_in[2];
    const float* q_scale = (const float*)d_in[3];
    const float* k_scale = (const float*)d_in[4];
    const float* w_out   = (const float*)d_in[5];
    float* out = (float*)d_out;

    if (ws_size < 4 * SZ * sizeof(float)) return;   // need 128 MiB scratch

    char* base = (char*)d_ws;
    ushort* xnhi = (ushort*)base;                              // 16 MB
    ushort* xnlo = (ushort*)(base + (size_t)16 * 1024 * 1024); // 16 MB
    float*  qb   = (float*)(base + (size_t)32 * 1024 * 1024);  // 32 MB
    float*  kb   = (float*)(base + (size_t)64 * 1024 * 1024);  // 32 MB
    float*  vb   = (float*)(base + (size_t)96 * 1024 * 1024);  // 32 MB
    ushort* Ohi  = xnhi;                                       // reuse (xn dead)
    ushort* Olo  = xnlo;
    // w_qkv^T planes live in d_out (scratch until out_gemm overwrites it)
    ushort* wqh = (ushort*)d_out;
    ushort* wql = wqh + (size_t)1536 * 512;
    // w_out^T planes live in vb region (dead after attn)
    ushort* woh = (ushort*)(base + (size_t)96 * 1024 * 1024);
    ushort* wol = woh + (size_t)512 * 512;

    split_w_k<<<dim3(48, 16), 256, 0, stream>>>(w_qkv, wqh, wql, 512, 1536);
    rmsnorm_k<<<TOKENS / 4, 256, 0, stream>>>(x, g, xnhi, xnlo);
    mfma_gemm_k<0><<<dim3(12, TOKENS / 128), 256, 0, stream>>>(xnhi, xnlo, wqh, wql, qb);
    qknorm_k<<<(TOKENS * HEADS) / 4, 256, 0, stream>>>(qb, q_scale);
    qknorm_k<<<(TOKENS * HEADS) / 4, 256, 0, stream>>>(kb, k_scale);
    attn_k<<<dim3(N_ / 128, B_ * HEADS), 256, 0, stream>>>(qb, kb, vb, Ohi, Olo);
    split_w_k<<<dim3(16, 16), 256, 0, stream>>>(w_out, woh, wol, 512, 512);
    mfma_gemm_k<1><<<dim3(4, TOKENS / 128), 256, 0, stream>>>(Ohi, Olo, woh, wol, out);
}